// Round 2
// baseline (2345.648 us; speedup 1.0000x reference)
//
#include <hip/hip_runtime.h>
#include <hip/hip_bf16.h>
#include <math.h>

// ---------------- static problem config ----------------
#define BB 4
#define LL 4096
#define DD 1024
#define KK 32
#define HH 32
#define AA 4
#define CKK 4
#define DI 1024
#define ZC 2080            // 2*DI + KK
#define FLATC 1024         // K*H
#define BL (BB * LL)       // 16384

// scan config
#define CH 256
#define NCH (LL / CH)      // 16

// ---------------- generic f32 tiled GEMM (used for z_s pre-pass and K5) ----
// C[M,N] = A[M,Kd] * B[Kd,N] with explicit leading dims.
#define GBM 64
#define GBN 64
#define GBK 16

__global__ __launch_bounds__(256) void gemm_f32_kernel(
    const float* __restrict__ A, const float* __restrict__ B,
    float* __restrict__ C, int M, int N, int Kd, int lda, int ldb, int ldc) {
  __shared__ float As[GBK][GBM + 4];   // transposed A tile (pitch 68 floats)
  __shared__ float Bs[GBK][GBN];
  const int tid = threadIdx.x;
  const int tx = tid & 15, ty = tid >> 4;
  const int bm = blockIdx.y * GBM, bn = blockIdx.x * GBN;
  float acc[4][4] = {};

  for (int k0 = 0; k0 < Kd; k0 += GBK) {
    {
      const int ar = tid >> 2;            // 0..63
      const int ac = (tid & 3) * 4;       // 0,4,8,12
      float4 av = *(const float4*)(A + (size_t)(bm + ar) * lda + k0 + ac);
      As[ac + 0][ar] = av.x;
      As[ac + 1][ar] = av.y;
      As[ac + 2][ar] = av.z;
      As[ac + 3][ar] = av.w;
    }
    {
      const int br = tid >> 4;            // 0..15
      const int bc = (tid & 15) * 4;      // 0..60
      const int gc = bn + bc;
      float4 bv = make_float4(0.f, 0.f, 0.f, 0.f);
      if (gc < N) bv = *(const float4*)(B + (size_t)(k0 + br) * ldb + gc);
      *(float4*)&Bs[br][bc] = bv;
    }
    __syncthreads();
#pragma unroll
    for (int kk = 0; kk < GBK; ++kk) {
      float4 a4 = *(const float4*)&As[kk][ty * 4];
      float4 b4 = *(const float4*)&Bs[kk][tx * 4];
      float aa[4] = {a4.x, a4.y, a4.z, a4.w};
      float bb[4] = {b4.x, b4.y, b4.z, b4.w};
#pragma unroll
      for (int i = 0; i < 4; ++i)
#pragma unroll
        for (int j = 0; j < 4; ++j) acc[i][j] = fmaf(aa[i], bb[j], acc[i][j]);
    }
    __syncthreads();
  }
#pragma unroll
  for (int i = 0; i < 4; ++i) {
    const int gr = bm + ty * 4 + i;
#pragma unroll
    for (int j = 0; j < 4; ++j) {
      const int gc = bn + tx * 4 + j;
      if (gc < N) C[(size_t)gr * ldc + gc] = acc[i][j];
    }
  }
}

// ---------------- p_w pre-pass: conv on z_s + time weights + exp ----------
// one thread per (row, k); grid = BL*KK/256
__global__ __launch_bounds__(256) void pw_kernel(
    const float* __restrict__ zs, const float* __restrict__ kern,
    const float* __restrict__ decay, const float* __restrict__ anchor,
    const float* __restrict__ sscale, float* __restrict__ pw,
    float* __restrict__ merged) {
  const int t = blockIdx.x * 256 + threadIdx.x;   // 0 .. BL*32-1
  const int k = t & (KK - 1);
  const int row = t >> 5;                          // global (b*LL + l)
  const int l = row & (LL - 1);
  float v = 0.f;
#pragma unroll
  for (int w = 0; w < CKK; ++w) {
    if (l - 3 + w >= 0)
      v = fmaf(zs[(size_t)(row - 3 + w) * KK + k], kern[w * ZC + 2 * DI + k], v);
  }
  const float slope = (k < KK - AA) ? decay[k] : anchor[k - (KK - AA)];
  const float sp = log1pf(__expf(slope));          // softplus
  const float lw = (k < KK - AA) ? (-sp * (float)(LL - 1 - l)) : (-sp * (float)l);
  const float p = __expf(sscale[k] * v + lw);
  pw[t] = p;
  merged[(size_t)row * ZC + k] = p;                // den channel
}

// ---------------- fused in-proj GEMM + causal conv + features -------------
// grid (32, 256): 32 column tiles over [0,2048), 256 row tiles of 64.
__global__ __launch_bounds__(256) void fused_in_feat_kernel(
    const float* __restrict__ x, const float* __restrict__ W_in,
    const float* __restrict__ kern, const float* __restrict__ theta,
    const float* __restrict__ pw, float* __restrict__ merged,
    __hip_bfloat16* __restrict__ gate) {
  __shared__ float As[GBK][GBM + 8];        // cols 0..63 main rows, 64..66 halo rows
  __shared__ float Bs[GBK][GBN];
  __shared__ float zt[67 * 68];             // conv input tile, pitch 68
  __shared__ float skern[CKK * 64];         // conv weights for this col tile
  __shared__ float stheta[64];

  const int tid = threadIdx.x;
  const int tx = tid & 15, ty = tid >> 4;
  const int bn = blockIdx.x * GBN;          // 0..1984 (cols of first 2048)
  const int bm = blockIdx.y * GBM;          // 0..16320 (rows of BL)
  const bool firstTile = ((bm & (LL - 1)) == 0);
  const bool isFeat = (bn < DI);

  // stage conv kernel weights + theta for this column tile
  skern[tid] = kern[(tid >> 6) * ZC + bn + (tid & 63)];
  if (isFeat && tid < 64) stheta[tid] = theta[bn + tid];

  float acc[4][4] = {};
  float hacc = 0.f;                          // halo accumulator (tid<192)

  for (int k0 = 0; k0 < DD; k0 += GBK) {
    {  // main A rows
      const int ar = tid >> 2;
      const int ac = (tid & 3) * 4;
      float4 av = *(const float4*)(x + (size_t)(bm + ar) * DD + k0 + ac);
      As[ac + 0][ar] = av.x;
      As[ac + 1][ar] = av.y;
      As[ac + 2][ar] = av.z;
      As[ac + 3][ar] = av.w;
    }
    if (tid < 12) {  // halo A rows (bm-3 .. bm-1), zero at batch start
      const int r = tid >> 2;
      const int ac = (tid & 3) * 4;
      float4 av = make_float4(0.f, 0.f, 0.f, 0.f);
      if (!firstTile)
        av = *(const float4*)(x + (size_t)(bm - 3 + r) * DD + k0 + ac);
      As[ac + 0][64 + r] = av.x;
      As[ac + 1][64 + r] = av.y;
      As[ac + 2][64 + r] = av.z;
      As[ac + 3][64 + r] = av.w;
    }
    {  // B tile from W_in (ldb = ZC), cols bn..bn+63 all < 2048, no guard
      const int br = tid >> 4;
      const int bc = (tid & 15) * 4;
      *(float4*)&Bs[br][bc] = *(const float4*)(W_in + (size_t)(k0 + br) * ZC + bn + bc);
    }
    __syncthreads();
#pragma unroll
    for (int kk = 0; kk < GBK; ++kk) {
      float4 a4 = *(const float4*)&As[kk][ty * 4];
      float4 b4 = *(const float4*)&Bs[kk][tx * 4];
      float aa[4] = {a4.x, a4.y, a4.z, a4.w};
      float bb[4] = {b4.x, b4.y, b4.z, b4.w};
#pragma unroll
      for (int i = 0; i < 4; ++i)
#pragma unroll
        for (int j = 0; j < 4; ++j) acc[i][j] = fmaf(aa[i], bb[j], acc[i][j]);
    }
    if (tid < 192) {  // halo GEMM: 3 rows x 64 cols
      const int hr = tid >> 6, hc = tid & 63;
#pragma unroll
      for (int kk = 0; kk < GBK; ++kk)
        hacc = fmaf(As[kk][64 + hr], Bs[kk][hc], hacc);
    }
    __syncthreads();
  }

  // write z-tile (conv input) to LDS: halo rows at 0..2, main at 3..66
  if (tid < 192) zt[(tid >> 6) * 68 + (tid & 63)] = hacc;
#pragma unroll
  for (int i = 0; i < 4; ++i) {
    float4 v = make_float4(acc[i][0], acc[i][1], acc[i][2], acc[i][3]);
    *(float4*)&zt[(3 + ty * 4 + i) * 68 + tx * 4] = v;
  }
  __syncthreads();

  // conv + epilogue: each thread owns rows ty*4+i, cols tx*4+j
  const float kw0[4] = {skern[0 * 64 + tx * 4 + 0], skern[0 * 64 + tx * 4 + 1],
                        skern[0 * 64 + tx * 4 + 2], skern[0 * 64 + tx * 4 + 3]};
  const float kw1[4] = {skern[1 * 64 + tx * 4 + 0], skern[1 * 64 + tx * 4 + 1],
                        skern[1 * 64 + tx * 4 + 2], skern[1 * 64 + tx * 4 + 3]};
  const float kw2[4] = {skern[2 * 64 + tx * 4 + 0], skern[2 * 64 + tx * 4 + 1],
                        skern[2 * 64 + tx * 4 + 2], skern[2 * 64 + tx * 4 + 3]};
  const float kw3[4] = {skern[3 * 64 + tx * 4 + 0], skern[3 * 64 + tx * 4 + 1],
                        skern[3 * 64 + tx * 4 + 2], skern[3 * 64 + tx * 4 + 3]};

#pragma unroll
  for (int i = 0; i < 4; ++i) {
    const int lrow = ty * 4 + i;               // local row
    const size_t grow = (size_t)(bm + lrow);   // global row
    float v[4];
#pragma unroll
    for (int j = 0; j < 4; ++j) {
      const int c = tx * 4 + j;
      float s = zt[(lrow + 0) * 68 + c] * kw0[j];
      s = fmaf(zt[(lrow + 1) * 68 + c], kw1[j], s);
      s = fmaf(zt[(lrow + 2) * 68 + c], kw2[j], s);
      s = fmaf(zt[(lrow + 3) * 68 + c], kw3[j], s);
      v[j] = s;
    }
    if (isFeat) {
      const float pwv = pw[grow * KK + ((bn + tx * 4) >> 5)];
      float re[4], im[4];
#pragma unroll
      for (int j = 0; j < 4; ++j) {
        const float phi = v[j] * stheta[tx * 4 + j];
        float sv, cv;
        __sincosf(phi, &sv, &cv);
        re[j] = pwv * cv;
        im[j] = pwv * sv;
      }
      float* rowp = merged + grow * ZC;
      *(float4*)&rowp[KK + bn + tx * 4] = make_float4(re[0], re[1], re[2], re[3]);
      *(float4*)&rowp[KK + FLATC + bn + tx * 4] = make_float4(im[0], im[1], im[2], im[3]);
    } else {
      ushort4 gv;
      unsigned short* gp = (unsigned short*)&gv;
#pragma unroll
      for (int j = 0; j < 4; ++j) {
        const float sil = v[j] * (1.0f / (1.0f + __expf(-v[j])));
        __hip_bfloat16 h = __float2bfloat16(sil);
        gp[j] = *(unsigned short*)&h;
      }
      *(ushort4*)&gate[grow * DI + (bn - DI) + tx * 4] = gv;
    }
  }
}

// ---------------- blocked scan over L (per batch, per channel) ------------
__global__ __launch_bounds__(256) void scan_partial_kernel(
    const float* __restrict__ merged, float* __restrict__ part) {
  const int c = blockIdx.x * 256 + threadIdx.x;
  const int chunk = blockIdx.y, b = blockIdx.z;
  if (c >= ZC) return;
  size_t base = ((size_t)b * LL + (size_t)chunk * CH) * ZC + c;
  float s = 0.f;
#pragma unroll 8
  for (int i = 0; i < CH; ++i) s += merged[base + (size_t)i * ZC];
  part[((size_t)b * NCH + chunk) * ZC + c] = s;
}

__global__ __launch_bounds__(256) void scan_offsets_kernel(float* __restrict__ part) {
  const int c = blockIdx.x * 256 + threadIdx.x;
  const int b = blockIdx.z;
  if (c >= ZC) return;
  float run = 0.f;
#pragma unroll
  for (int i = 0; i < NCH; ++i) {
    const size_t idx = ((size_t)b * NCH + i) * ZC + c;
    const float t = part[idx];
    part[idx] = run;
    run += t;
  }
}

__global__ __launch_bounds__(256) void scan_apply_kernel(
    float* __restrict__ merged, const float* __restrict__ part) {
  const int c = blockIdx.x * 256 + threadIdx.x;
  const int chunk = blockIdx.y, b = blockIdx.z;
  if (c >= ZC) return;
  float s = part[((size_t)b * NCH + chunk) * ZC + c];
  size_t base = ((size_t)b * LL + (size_t)chunk * CH) * ZC + c;
#pragma unroll 4
  for (int i = 0; i < CH; ++i) {
    const size_t idx = base + (size_t)i * ZC;
    s += merged[idx];
    merged[idx] = s;
  }
}

// ---------------- normalize + RMS + head matmuls + gate -------------------
// Writes g IN-PLACE into merged row [0, DI)  (reads complete before writes).
__global__ __launch_bounds__(256) void norm_head_kernel(
    float* merged_rows, const __hip_bfloat16* gate,
    const float* __restrict__ W_re, const float* __restrict__ W_im,
    const float* __restrict__ norm_scale) {
  const int bl = blockIdx.x;
  float* row = merged_rows + (size_t)bl * ZC;
  __shared__ float sre[FLATC], sim[FLATC];
  __shared__ float sWre[FLATC], sWim[FLATC];
  __shared__ float sns[2 * HH];
  __shared__ float sinv[KK], srs[KK];
  const int tid = threadIdx.x;

  for (int i = tid; i < FLATC; i += 256) { sWre[i] = W_re[i]; sWim[i] = W_im[i]; }
  if (tid < 2 * HH) sns[tid] = norm_scale[tid];
  if (tid < KK) sinv[tid] = 1.0f / fmaxf(row[tid], 1e-4f);
  __syncthreads();

  for (int c = tid; c < FLATC; c += 256) {
    const float inv = sinv[c >> 5];
    sre[c] = row[KK + c] * inv;
    sim[c] = row[KK + FLATC + c] * inv;
  }
  __syncthreads();

  if (tid < KK) {
    float s = 0.f;
#pragma unroll
    for (int h = 0; h < HH; ++h) {
      const float r = sre[tid * HH + h], i2 = sim[tid * HH + h];
      s = fmaf(r, r, fmaf(i2, i2, s));
    }
    srs[tid] = rsqrtf(s * (1.0f / (2.0f * HH)) + 1e-5f);
  }
  __syncthreads();

  const __hip_bfloat16* grow = gate + (size_t)bl * DI;
  for (int o = tid; o < DI; o += 256) {
    const int k = o >> 5, h = o & 31;
    float acc = 0.f;
#pragma unroll
    for (int hp = 0; hp < HH; ++hp) {
      acc = fmaf(sre[k * HH + hp] * sns[hp], sWre[hp * HH + h], acc);
      acc = fmaf(sim[k * HH + hp] * sns[HH + hp], sWim[hp * HH + h], acc);
    }
    row[o] = acc * srs[k] * __bfloat162float(grow[o]);
  }
}

// ---------------- launch ----------------
extern "C" void kernel_launch(void* const* d_in, const int* in_sizes, int n_in,
                              void* d_out, int out_size, void* d_ws, size_t ws_size,
                              hipStream_t stream) {
  const float* x      = (const float*)d_in[0];
  const float* W_in   = (const float*)d_in[1];
  const float* kern   = (const float*)d_in[2];
  const float* theta  = (const float*)d_in[3];
  const float* decay  = (const float*)d_in[4];
  const float* anchor = (const float*)d_in[5];
  const float* sscale = (const float*)d_in[6];
  const float* W_re   = (const float*)d_in[7];
  const float* W_im   = (const float*)d_in[8];
  const float* nscale = (const float*)d_in[9];
  const float* W_out  = (const float*)d_in[10];
  float* out = (float*)d_out;

  // workspace layout (~175 MB total)
  float* merged = (float*)d_ws;                               // BL*ZC f32
  __hip_bfloat16* gate = (__hip_bfloat16*)(merged + (size_t)BL * ZC);  // BL*DI bf16
  float* zs   = (float*)(gate + (size_t)BL * DI);             // BL*KK f32
  float* pw   = zs + (size_t)BL * KK;                         // BL*KK f32
  float* part = pw + (size_t)BL * KK;                         // BB*NCH*ZC f32

  // 1) z_s = x @ W_in[:, 2048:2080]   [BL,32]
  {
    dim3 grid(1, BL / GBM);
    gemm_f32_kernel<<<grid, 256, 0, stream>>>(x, W_in + 2 * DI, zs,
                                              BL, KK, DD, DD, ZC, KK);
  }
  // 2) p_w from z_s (conv + time weights + exp); also writes den channel
  {
    pw_kernel<<<dim3(BL * KK / 256), 256, 0, stream>>>(zs, kern, decay, anchor,
                                                       sscale, pw, merged);
  }
  // 3) fused in-proj GEMM + conv + features -> merged re/im + gate(bf16)
  {
    dim3 grid(2 * DI / GBN, BL / GBM);  // (32, 256)
    fused_in_feat_kernel<<<grid, 256, 0, stream>>>(x, W_in, kern, theta, pw,
                                                   merged, gate);
  }
  // 4) blocked inclusive scan over L (in-place on merged)
  {
    dim3 grid((ZC + 255) / 256, NCH, BB);
    scan_partial_kernel<<<grid, 256, 0, stream>>>(merged, part);
    dim3 grid2((ZC + 255) / 256, 1, BB);
    scan_offsets_kernel<<<grid2, 256, 0, stream>>>(part);
    scan_apply_kernel<<<grid, 256, 0, stream>>>(merged, part);
  }
  // 5) normalize + RMS + head matmuls + gate -> g (in-place, merged[:,0:DI])
  {
    norm_head_kernel<<<dim3(BL), 256, 0, stream>>>(merged, gate, W_re, W_im,
                                                   nscale);
  }
  // 6) out = g @ W_out   (g rows have stride ZC inside merged)
  {
    dim3 grid(DD / GBN, BL / GBM);
    gemm_f32_kernel<<<grid, 256, 0, stream>>>(merged, W_out, out,
                                              BL, DD, DI, ZC, DD, DD);
  }
}

// Round 3
// 778.530 us; speedup vs baseline: 3.0129x; 3.0129x over previous
//
#include <hip/hip_runtime.h>
#include <hip/hip_bf16.h>
#include <math.h>

// ---------------- static problem config ----------------
#define BB 4
#define LL 4096
#define DD 1024
#define KK 32
#define HH 32
#define AA 4
#define CKK 4
#define DI 1024
#define ZC 2080            // 2*DI + KK
#define FLATC 1024         // K*H
#define BL (BB * LL)       // 16384
#define ZLD 2080           // z row stride (bf16)
#define NPAD 2176          // W_in^T padded rows (17*128)

// scan config
#define CH 256
#define NCH (LL / CH)      // 16

typedef unsigned short u16;
typedef __attribute__((ext_vector_type(8))) short s16x8;
typedef __attribute__((ext_vector_type(4))) float f32x4;

__device__ __forceinline__ u16 f2bf(float f) {
  union { float f; unsigned int u; } v; v.f = f;
  unsigned int r = (v.u + 0x7FFFu + ((v.u >> 16) & 1u)) >> 16;
  return (u16)r;
}
__device__ __forceinline__ float bf2f(u16 u) {
  union { unsigned int i; float f; } x; x.i = ((unsigned int)u) << 16; return x.f;
}
__device__ __forceinline__ void gl_lds16(const void* g, void* l) {
  __builtin_amdgcn_global_load_lds(
      (const __attribute__((address_space(1))) unsigned int*)g,
      (__attribute__((address_space(3))) unsigned int*)l, 16, 0, 0);
}

// ---------------- cast f32 -> bf16 (x) ----------------
__global__ __launch_bounds__(256) void cast_bf16_kernel(
    const float* __restrict__ src, u16* __restrict__ dst, int n) {
  const int i = (blockIdx.x * 256 + threadIdx.x) * 8;
  if (i >= n) return;
  float4 a = *(const float4*)(src + i);
  float4 b = *(const float4*)(src + i + 4);
  s16x8 v;
  v[0] = (short)f2bf(a.x); v[1] = (short)f2bf(a.y);
  v[2] = (short)f2bf(a.z); v[3] = (short)f2bf(a.w);
  v[4] = (short)f2bf(b.x); v[5] = (short)f2bf(b.y);
  v[6] = (short)f2bf(b.z); v[7] = (short)f2bf(b.w);
  *(s16x8*)(dst + i) = v;
}

// ---------------- transpose + cast: src[R][C] f32 -> dst[Cpad][R] bf16 ----
__global__ __launch_bounds__(256) void transpose_cast_kernel(
    const float* __restrict__ src, u16* __restrict__ dst,
    int R, int C, int Cpad) {
  __shared__ float t[32][33];
  const int tid = threadIdx.x;
  const int r0 = blockIdx.x * 32, c0 = blockIdx.y * 32;
  const int lr = tid >> 5, lc = tid & 31;
#pragma unroll
  for (int i = 0; i < 4; ++i) {
    const int r = r0 + i * 8 + lr, c = c0 + lc;
    float v = 0.f;
    if (r < R && c < C) v = src[(size_t)r * C + c];
    t[lc][i * 8 + lr] = v;
  }
  __syncthreads();
#pragma unroll
  for (int i = 0; i < 4; ++i) {
    const int dr = c0 + i * 8 + lr;   // row in dst = col in src
    const int dc = r0 + lc;           // col in dst = row in src
    if (dr < Cpad && dc < R) dst[(size_t)dr * R + dc] = f2bf(t[i * 8 + lr][lc]);
  }
}

// ---------------- bf16 MFMA GEMM: C[M,N] = A[M,K] * Bt[N,K]^T -------------
// 128x128 tile, 4 waves in 2x2, 16x16x32 MFMA, BK=64, global_load_lds(16B).
// LDS fragment-major: block (t16, kt) of 16x32 elems stored in lane order
// lane = q*16 + m -> elem (m, q*8..q*8+7). M % 128 == 0; N tiles padded in Bt.
template <int OUT_BF16>
__global__ __launch_bounds__(256) void gemm_bf16_mfma(
    const u16* __restrict__ A, const u16* __restrict__ Bt, void* __restrict__ C,
    int lda, int ldb, int ldc, int Kd, int Ncols) {
  __shared__ u16 As[8192];   // 16 blocks x 512 elems
  __shared__ u16 Bs[8192];
  const int tid = threadIdx.x;
  const int lane = tid & 63, wv = tid >> 6;
  const int lm = lane & 15, lq = lane >> 4;
  const int bm = blockIdx.y * 128, bn = blockIdx.x * 128;
  const int wrow = (wv & 1) * 64, wcol = (wv >> 1) * 64;

  const f32x4 z4 = {0.f, 0.f, 0.f, 0.f};
  f32x4 acc[4][4];
#pragma unroll
  for (int i = 0; i < 4; ++i)
#pragma unroll
    for (int j = 0; j < 4; ++j) acc[i][j] = z4;

  for (int k0 = 0; k0 < Kd; k0 += 64) {
    __syncthreads();
#pragma unroll
    for (int t = 0; t < 8; ++t) {
      const int idx = wv * 8 + t;             // 0..31
      if (idx < 16) {                          // A block (mt, kt)
        const int mt = idx >> 1, kt = idx & 1;
        const u16* g = A + (size_t)(bm + mt * 16 + lm) * lda + k0 + kt * 32 + lq * 8;
        gl_lds16(g, &As[idx * 512]);
      } else {                                 // B block (nt, kt)
        const int bidx = idx - 16;
        const int nt = bidx >> 1, kt = bidx & 1;
        const u16* g = Bt + (size_t)(bn + nt * 16 + lm) * ldb + k0 + kt * 32 + lq * 8;
        gl_lds16(g, &Bs[bidx * 512]);
      }
    }
    __syncthreads();
#pragma unroll
    for (int kt = 0; kt < 2; ++kt) {
      s16x8 af[4], bfb[4];
#pragma unroll
      for (int i = 0; i < 4; ++i) {
        const int mt = (wrow >> 4) + i;
        af[i] = *(const s16x8*)&As[(mt * 2 + kt) * 512 + lane * 8];
        const int nt = (wcol >> 4) + i;
        bfb[i] = *(const s16x8*)&Bs[(nt * 2 + kt) * 512 + lane * 8];
      }
#pragma unroll
      for (int i = 0; i < 4; ++i)
#pragma unroll
        for (int j = 0; j < 4; ++j)
          acc[i][j] = __builtin_amdgcn_mfma_f32_16x16x32_bf16(af[i], bfb[j], acc[i][j], 0, 0, 0);
    }
  }
  // epilogue: C/D layout col = lane&15, row = (lane>>4)*4 + reg
#pragma unroll
  for (int i = 0; i < 4; ++i) {
#pragma unroll
    for (int j = 0; j < 4; ++j) {
#pragma unroll
      for (int r = 0; r < 4; ++r) {
        const int row = bm + wrow + i * 16 + lq * 4 + r;
        const int col = bn + wcol + j * 16 + lm;
        if (col < Ncols) {
          if (OUT_BF16)
            ((u16*)C)[(size_t)row * ldc + col] = f2bf(acc[i][j][r]);
          else
            ((float*)C)[(size_t)row * ldc + col] = acc[i][j][r];
        }
      }
    }
  }
}

// ---------------- conv + p_w + phase features (reads z bf16) --------------
// block = 8 seq rows, all channels. Window rows r0-3 .. r0+7 staged in LDS.
__global__ __launch_bounds__(256) void conv_feat_kernel(
    const u16* __restrict__ z, const float* __restrict__ kern,
    const float* __restrict__ theta, const float* __restrict__ decay,
    const float* __restrict__ anchor, const float* __restrict__ sscale,
    float* __restrict__ merged) {
  __shared__ u16 zw[11 * ZLD];    // 45760 B
  __shared__ float spw[8][32];
  const int tid = threadIdx.x;
  const int r0 = blockIdx.x * 8;
  const bool first = ((r0 & (LL - 1)) == 0);

  for (int idx = tid; idx < 11 * (ZLD / 8); idx += 256) {
    const int i = idx / (ZLD / 8);
    const int c8 = idx - i * (ZLD / 8);
    s16x8 v = {0, 0, 0, 0, 0, 0, 0, 0};
    if (!(first && i < 3))
      v = *(const s16x8*)(z + (size_t)(r0 - 3 + i) * ZLD + c8 * 8);
    *(s16x8*)&zw[i * ZLD + c8 * 8] = v;
  }
  __syncthreads();

  {  // scores -> p_w (8 rows x 32 heads = 256 threads)
    const int rr = tid >> 5, k = tid & 31;
    float v = 0.f;
#pragma unroll
    for (int w = 0; w < CKK; ++w)
      v = fmaf(bf2f(zw[(rr + w) * ZLD + 2048 + k]), kern[w * ZC + 2048 + k], v);
    const int l = (r0 + rr) & (LL - 1);
    const float slope = (k < KK - AA) ? decay[k] : anchor[k - (KK - AA)];
    const float sp = log1pf(__expf(slope));
    const float lw = (k < KK - AA) ? (-sp * (float)(LL - 1 - l)) : (-sp * (float)l);
    const float p = __expf(sscale[k] * v + lw);
    spw[rr][k] = p;
    merged[(size_t)(r0 + rr) * ZC + k] = p;
  }
  __syncthreads();

#pragma unroll 1
  for (int it = 0; it < 4; ++it) {
    const int c = it * 256 + tid;   // 0..1023
    const float kw0 = kern[0 * ZC + c], kw1 = kern[1 * ZC + c];
    const float kw2 = kern[2 * ZC + c], kw3 = kern[3 * ZC + c];
    const float th = theta[c];
    float zv[11];
#pragma unroll
    for (int i = 0; i < 11; ++i) zv[i] = bf2f(zw[i * ZLD + c]);
#pragma unroll
    for (int rr = 0; rr < 8; ++rr) {
      float v = zv[rr] * kw0;
      v = fmaf(zv[rr + 1], kw1, v);
      v = fmaf(zv[rr + 2], kw2, v);
      v = fmaf(zv[rr + 3], kw3, v);
      const float phi = v * th;
      float sv, cv;
      __sincosf(phi, &sv, &cv);
      const float p = spw[rr][c >> 5];
      float* mrow = merged + (size_t)(r0 + rr) * ZC;
      mrow[KK + c] = p * cv;
      mrow[KK + FLATC + c] = p * sv;
    }
  }
}

// ---------------- blocked scan over L ----------------
__global__ __launch_bounds__(256) void scan_partial_kernel(
    const float* __restrict__ merged, float* __restrict__ part) {
  const int c = blockIdx.x * 256 + threadIdx.x;
  const int chunk = blockIdx.y, b = blockIdx.z;
  if (c >= ZC) return;
  size_t base = ((size_t)b * LL + (size_t)chunk * CH) * ZC + c;
  float s = 0.f;
#pragma unroll 8
  for (int i = 0; i < CH; ++i) s += merged[base + (size_t)i * ZC];
  part[((size_t)b * NCH + chunk) * ZC + c] = s;
}

__global__ __launch_bounds__(256) void scan_offsets_kernel(float* __restrict__ part) {
  const int c = blockIdx.x * 256 + threadIdx.x;
  const int b = blockIdx.z;
  if (c >= ZC) return;
  float run = 0.f;
#pragma unroll
  for (int i = 0; i < NCH; ++i) {
    const size_t idx = ((size_t)b * NCH + i) * ZC + c;
    const float t = part[idx];
    part[idx] = run;
    run += t;
  }
}

__global__ __launch_bounds__(256) void scan_apply_kernel(
    float* __restrict__ merged, const float* __restrict__ part) {
  const int c = blockIdx.x * 256 + threadIdx.x;
  const int chunk = blockIdx.y, b = blockIdx.z;
  if (c >= ZC) return;
  float s = part[((size_t)b * NCH + chunk) * ZC + c];
  size_t base = ((size_t)b * LL + (size_t)chunk * CH) * ZC + c;
#pragma unroll 4
  for (int i = 0; i < CH; ++i) {
    const size_t idx = base + (size_t)i * ZC;
    s += merged[idx];
    merged[idx] = s;
  }
}

// ---------------- normalize + RMS + head matmuls + gate -------------------
// Computes gate = silu(conv(z cols 1024..2047)) itself; writes g as bf16
// IN-PLACE into the head of its merged row (all reads precede writes).
__global__ __launch_bounds__(256) void norm_head_kernel(
    float* merged, const u16* __restrict__ z, const float* __restrict__ kern,
    const float* __restrict__ W_re, const float* __restrict__ W_im,
    const float* __restrict__ norm_scale) {
  const int bl = blockIdx.x;
  const int l = bl & (LL - 1);
  float* row = merged + (size_t)bl * ZC;
  __shared__ float sre[FLATC], sim[FLATC];
  __shared__ float sWre[FLATC], sWim[FLATC];
  __shared__ float sns[2 * HH];
  __shared__ float sinv[KK], srs[KK];
  const int tid = threadIdx.x;

  for (int i = tid; i < FLATC; i += 256) { sWre[i] = W_re[i]; sWim[i] = W_im[i]; }
  if (tid < 2 * HH) sns[tid] = norm_scale[tid];
  if (tid < KK) sinv[tid] = 1.0f / fmaxf(row[tid], 1e-4f);
  __syncthreads();

  for (int c = tid; c < FLATC; c += 256) {
    const float inv = sinv[c >> 5];
    sre[c] = row[KK + c] * inv;
    sim[c] = row[KK + FLATC + c] * inv;
  }
  __syncthreads();

  if (tid < KK) {
    float s = 0.f;
#pragma unroll
    for (int h = 0; h < HH; ++h) {
      const float r = sre[tid * HH + h], i2 = sim[tid * HH + h];
      s = fmaf(r, r, fmaf(i2, i2, s));
    }
    srs[tid] = rsqrtf(s * (1.0f / (2.0f * HH)) + 1e-5f);
  }
  __syncthreads();

  u16* grow = (u16*)row;   // g bf16 overwrites row head (reads are done)
  for (int o = tid; o < DI; o += 256) {
    const int k = o >> 5, h = o & 31;
    float acc = 0.f;
#pragma unroll
    for (int hp = 0; hp < HH; ++hp) {
      acc = fmaf(sre[k * HH + hp] * sns[hp], sWre[hp * HH + h], acc);
      acc = fmaf(sim[k * HH + hp] * sns[HH + hp], sWim[hp * HH + h], acc);
    }
    float gv = 0.f;
#pragma unroll
    for (int w = 0; w < CKK; ++w) {
      const int lr = l - 3 + w;
      if (lr >= 0)
        gv = fmaf(bf2f(z[(size_t)(bl - 3 + w) * ZLD + DI + o]),
                  kern[w * ZC + DI + o], gv);
    }
    const float sil = gv * (1.0f / (1.0f + __expf(-gv)));
    grow[o] = f2bf(acc * srs[k] * sil);
  }
}

// ---------------- launch ----------------
extern "C" void kernel_launch(void* const* d_in, const int* in_sizes, int n_in,
                              void* d_out, int out_size, void* d_ws, size_t ws_size,
                              hipStream_t stream) {
  const float* x      = (const float*)d_in[0];
  const float* W_in   = (const float*)d_in[1];
  const float* kern   = (const float*)d_in[2];
  const float* theta  = (const float*)d_in[3];
  const float* decay  = (const float*)d_in[4];
  const float* anchor = (const float*)d_in[5];
  const float* sscale = (const float*)d_in[6];
  const float* W_re   = (const float*)d_in[7];
  const float* W_im   = (const float*)d_in[8];
  const float* nscale = (const float*)d_in[9];
  const float* W_out  = (const float*)d_in[10];
  float* out = (float*)d_out;

  // workspace layout (~199.8 MiB):
  //   merged : BL*ZC f32           136,314,880 B  (xbf aliases its head)
  //   zbf    : BL*ZLD bf16          68,157,440 B  (wobt aliases its head, late)
  //   wbt    : NPAD*DD bf16          4,456,448 B
  //   part   : BB*NCH*ZC f32           532,480 B
  char* w = (char*)d_ws;
  float* merged = (float*)w;
  u16* xbf = (u16*)w;                                  // alias: dead once gemm1 done
  u16* zbf = (u16*)(w + (size_t)BL * ZC * 4);
  u16* wobt = zbf;                                     // alias: written after norm_head
  u16* wbt = (u16*)(w + (size_t)BL * ZC * 4 + (size_t)BL * ZLD * 2);
  float* part = (float*)((char*)wbt + (size_t)NPAD * DD * 2);

  // 1) casts / transposes
  cast_bf16_kernel<<<dim3(BL * DD / 8 / 256), 256, 0, stream>>>(x, xbf, BL * DD);
  transpose_cast_kernel<<<dim3(32, 68), 256, 0, stream>>>(W_in, wbt, DD, ZC, NPAD);

  // 2) GEMM1: z = x @ W_in  (bf16 MFMA, bf16 out, guarded to 2080 cols)
  gemm_bf16_mfma<1><<<dim3(NPAD / 128, BL / 128), 256, 0, stream>>>(
      xbf, wbt, zbf, DD, DD, ZLD, DD, ZC);

  // 3) conv + p_w + features -> merged
  conv_feat_kernel<<<dim3(BL / 8), 256, 0, stream>>>(zbf, kern, theta, decay,
                                                     anchor, sscale, merged);

  // 4) blocked inclusive scan over L (in-place on merged)
  {
    dim3 grid((ZC + 255) / 256, NCH, BB);
    scan_partial_kernel<<<grid, 256, 0, stream>>>(merged, part);
    dim3 grid2((ZC + 255) / 256, 1, BB);
    scan_offsets_kernel<<<grid2, 256, 0, stream>>>(part);
    scan_apply_kernel<<<grid, 256, 0, stream>>>(merged, part);
  }

  // 5) normalize + RMS + head matmuls + gate -> g (bf16, in merged row head)
  norm_head_kernel<<<dim3(BL), 256, 0, stream>>>(merged, zbf, kern, W_re, W_im,
                                                 nscale);

  // 6) W_out^T (into dead z region), then GEMM2: out = g @ W_out (f32 out)
  transpose_cast_kernel<<<dim3(32, 32), 256, 0, stream>>>(W_out, wobt, DI, DD, DD);
  gemm_bf16_mfma<0><<<dim3(DD / 128, BL / 128), 256, 0, stream>>>(
      (const u16*)merged, wobt, out, 2 * ZC, DI, DD, DI, DD);
}

// Round 6
// 522.628 us; speedup vs baseline: 4.4882x; 1.4896x over previous
//
#include <hip/hip_runtime.h>
#include <hip/hip_bf16.h>
#include <math.h>

// ---------------- static problem config ----------------
#define BB 4
#define LL 4096
#define DD 1024
#define KK 32
#define HH 32
#define AA 4
#define CKK 4
#define DI 1024
#define ZC 2080            // 2*DI + KK
#define FLATC 1024         // K*H
#define BL (BB * LL)       // 16384
#define ZLD 2080           // z row stride (bf16)
#define NPAD 2176          // W_in^T padded rows (17*128)

// scan config
#define CH 256
#define NCH (LL / CH)      // 16

// norm_head LDS strides (skewed to break lq-stride-128 bank conflicts)
#define GLD 1136           // zw row stride in u16 : col = o + (o>>7)*16
#define KLD 1080           // skern row stride in f32: col = o + (o>>7)*8

typedef unsigned short u16;
typedef __attribute__((ext_vector_type(8))) short s16x8;
typedef __attribute__((ext_vector_type(4))) float f32x4;

__device__ __forceinline__ u16 f2bf(float f) {
  union { float f; unsigned int u; } v; v.f = f;
  unsigned int r = (v.u + 0x7FFFu + ((v.u >> 16) & 1u)) >> 16;
  return (u16)r;
}
__device__ __forceinline__ float bf2f(u16 u) {
  union { unsigned int i; float f; } x; x.i = ((unsigned int)u) << 16; return x.f;
}
__device__ __forceinline__ void gl_lds16(const void* g, void* l) {
  __builtin_amdgcn_global_load_lds(
      (const __attribute__((address_space(1))) unsigned int*)g,
      (__attribute__((address_space(3))) unsigned int*)l, 16, 0, 0);
}

// ---------------- cast f32 -> bf16 (x) ----------------
__global__ __launch_bounds__(256) void cast_bf16_kernel(
    const float* __restrict__ src, u16* __restrict__ dst, int n) {
  const int i = (blockIdx.x * 256 + threadIdx.x) * 8;
  if (i >= n) return;
  float4 a = *(const float4*)(src + i);
  float4 b = *(const float4*)(src + i + 4);
  s16x8 v;
  v[0] = (short)f2bf(a.x); v[1] = (short)f2bf(a.y);
  v[2] = (short)f2bf(a.z); v[3] = (short)f2bf(a.w);
  v[4] = (short)f2bf(b.x); v[5] = (short)f2bf(b.y);
  v[6] = (short)f2bf(b.z); v[7] = (short)f2bf(b.w);
  *(s16x8*)(dst + i) = v;
}

// ---------------- transpose + cast: src[R][C] f32 -> dst[Cpad][R] bf16 ----
__global__ __launch_bounds__(256) void transpose_cast_kernel(
    const float* __restrict__ src, u16* __restrict__ dst,
    int R, int C, int Cpad) {
  __shared__ float t[32][33];
  const int tid = threadIdx.x;
  const int r0 = blockIdx.x * 32, c0 = blockIdx.y * 32;
  const int lr = tid >> 5, lc = tid & 31;
#pragma unroll
  for (int i = 0; i < 4; ++i) {
    const int r = r0 + i * 8 + lr, c = c0 + lc;
    float v = 0.f;
    if (r < R && c < C) v = src[(size_t)r * C + c];
    t[lc][i * 8 + lr] = v;
  }
  __syncthreads();
#pragma unroll
  for (int i = 0; i < 4; ++i) {
    const int dr = c0 + i * 8 + lr;   // row in dst = col in src
    const int dc = r0 + lc;           // col in dst = row in src
    if (dr < Cpad && dc < R) dst[(size_t)dr * R + dc] = f2bf(t[i * 8 + lr][lc]);
  }
}

// ---------------- bf16 MFMA GEMM: C[M,N] = A[M,K] * Bt[N,K]^T -------------
// 128x128 tile, 4 waves in 2x2, 16x16x32 MFMA, BK=64, global_load_lds(16B).
template <int OUT_BF16>
__global__ __launch_bounds__(256) void gemm_bf16_mfma(
    const u16* __restrict__ A, const u16* __restrict__ Bt, void* __restrict__ C,
    int lda, int ldb, int ldc, int Kd, int Ncols) {
  __shared__ u16 As[8192];   // 16 blocks x 512 elems
  __shared__ u16 Bs[8192];
  const int tid = threadIdx.x;
  const int lane = tid & 63, wv = tid >> 6;
  const int lm = lane & 15, lq = lane >> 4;
  const int bm = blockIdx.y * 128, bn = blockIdx.x * 128;
  const int wrow = (wv & 1) * 64, wcol = (wv >> 1) * 64;

  const f32x4 z4 = {0.f, 0.f, 0.f, 0.f};
  f32x4 acc[4][4];
#pragma unroll
  for (int i = 0; i < 4; ++i)
#pragma unroll
    for (int j = 0; j < 4; ++j) acc[i][j] = z4;

  for (int k0 = 0; k0 < Kd; k0 += 64) {
    __syncthreads();
#pragma unroll
    for (int t = 0; t < 8; ++t) {
      const int idx = wv * 8 + t;             // 0..31
      if (idx < 16) {                          // A block (mt, kt)
        const int mt = idx >> 1, kt = idx & 1;
        const u16* g = A + (size_t)(bm + mt * 16 + lm) * lda + k0 + kt * 32 + lq * 8;
        gl_lds16(g, &As[idx * 512]);
      } else {                                 // B block (nt, kt)
        const int bidx = idx - 16;
        const int nt = bidx >> 1, kt = bidx & 1;
        const u16* g = Bt + (size_t)(bn + nt * 16 + lm) * ldb + k0 + kt * 32 + lq * 8;
        gl_lds16(g, &Bs[bidx * 512]);
      }
    }
    __syncthreads();
#pragma unroll
    for (int kt = 0; kt < 2; ++kt) {
      s16x8 af[4], bfb[4];
#pragma unroll
      for (int i = 0; i < 4; ++i) {
        const int mt = (wrow >> 4) + i;
        af[i] = *(const s16x8*)&As[(mt * 2 + kt) * 512 + lane * 8];
        const int nt = (wcol >> 4) + i;
        bfb[i] = *(const s16x8*)&Bs[(nt * 2 + kt) * 512 + lane * 8];
      }
#pragma unroll
      for (int i = 0; i < 4; ++i)
#pragma unroll
        for (int j = 0; j < 4; ++j)
          acc[i][j] = __builtin_amdgcn_mfma_f32_16x16x32_bf16(af[i], bfb[j], acc[i][j], 0, 0, 0);
    }
  }
  // epilogue: C/D layout col = lane&15, row = (lane>>4)*4 + reg
#pragma unroll
  for (int i = 0; i < 4; ++i) {
#pragma unroll
    for (int j = 0; j < 4; ++j) {
#pragma unroll
      for (int r = 0; r < 4; ++r) {
        const int row = bm + wrow + i * 16 + lq * 4 + r;
        const int col = bn + wcol + j * 16 + lm;
        if (col < Ncols) {
          if (OUT_BF16)
            ((u16*)C)[(size_t)row * ldc + col] = f2bf(acc[i][j][r]);
          else
            ((float*)C)[(size_t)row * ldc + col] = acc[i][j][r];
        }
      }
    }
  }
}

// ---------------- conv + p_w + phase features (reads z bf16) --------------
__global__ __launch_bounds__(256) void conv_feat_kernel(
    const u16* __restrict__ z, const float* __restrict__ kern,
    const float* __restrict__ theta, const float* __restrict__ decay,
    const float* __restrict__ anchor, const float* __restrict__ sscale,
    float* __restrict__ merged) {
  __shared__ u16 zw[11 * ZLD];    // 45760 B
  __shared__ float spw[8][32];
  const int tid = threadIdx.x;
  const int r0 = blockIdx.x * 8;
  const bool first = ((r0 & (LL - 1)) == 0);

  for (int idx = tid; idx < 11 * (ZLD / 8); idx += 256) {
    const int i = idx / (ZLD / 8);
    const int c8 = idx - i * (ZLD / 8);
    s16x8 v = {0, 0, 0, 0, 0, 0, 0, 0};
    if (!(first && i < 3))
      v = *(const s16x8*)(z + (size_t)(r0 - 3 + i) * ZLD + c8 * 8);
    *(s16x8*)&zw[i * ZLD + c8 * 8] = v;
  }
  __syncthreads();

  {  // scores -> p_w (8 rows x 32 heads = 256 threads)
    const int rr = tid >> 5, k = tid & 31;
    float v = 0.f;
#pragma unroll
    for (int w = 0; w < CKK; ++w)
      v = fmaf(bf2f(zw[(rr + w) * ZLD + 2048 + k]), kern[w * ZC + 2048 + k], v);
    const int l = (r0 + rr) & (LL - 1);
    const float slope = (k < KK - AA) ? decay[k] : anchor[k - (KK - AA)];
    const float sp = log1pf(__expf(slope));
    const float lw = (k < KK - AA) ? (-sp * (float)(LL - 1 - l)) : (-sp * (float)l);
    const float p = __expf(sscale[k] * v + lw);
    spw[rr][k] = p;
    merged[(size_t)(r0 + rr) * ZC + k] = p;
  }
  __syncthreads();

#pragma unroll 1
  for (int it = 0; it < 4; ++it) {
    const int c = it * 256 + tid;   // 0..1023
    const float kw0 = kern[0 * ZC + c], kw1 = kern[1 * ZC + c];
    const float kw2 = kern[2 * ZC + c], kw3 = kern[3 * ZC + c];
    const float th = theta[c];
    float zv[11];
#pragma unroll
    for (int i = 0; i < 11; ++i) zv[i] = bf2f(zw[i * ZLD + c]);
#pragma unroll
    for (int rr = 0; rr < 8; ++rr) {
      float v = zv[rr] * kw0;
      v = fmaf(zv[rr + 1], kw1, v);
      v = fmaf(zv[rr + 2], kw2, v);
      v = fmaf(zv[rr + 3], kw3, v);
      const float phi = v * th;
      float sv, cv;
      __sincosf(phi, &sv, &cv);
      const float p = spw[rr][c >> 5];
      float* mrow = merged + (size_t)(r0 + rr) * ZC;
      mrow[KK + c] = p * cv;
      mrow[KK + FLATC + c] = p * sv;
    }
  }
}

// ---------------- blocked scan over L ----------------
__global__ __launch_bounds__(256) void scan_partial_kernel(
    const float* __restrict__ merged, float* __restrict__ part) {
  const int c = blockIdx.x * 256 + threadIdx.x;
  const int chunk = blockIdx.y, b = blockIdx.z;
  if (c >= ZC) return;
  size_t base = ((size_t)b * LL + (size_t)chunk * CH) * ZC + c;
  float s = 0.f;
#pragma unroll 8
  for (int i = 0; i < CH; ++i) s += merged[base + (size_t)i * ZC];
  part[((size_t)b * NCH + chunk) * ZC + c] = s;
}

__global__ __launch_bounds__(256) void scan_offsets_kernel(float* __restrict__ part) {
  const int c = blockIdx.x * 256 + threadIdx.x;
  const int b = blockIdx.z;
  if (c >= ZC) return;
  float run = 0.f;
#pragma unroll
  for (int i = 0; i < NCH; ++i) {
    const size_t idx = ((size_t)b * NCH + i) * ZC + c;
    const float t = part[idx];
    part[idx] = run;
    run += t;
  }
}

__global__ __launch_bounds__(256) void scan_apply_kernel(
    float* __restrict__ merged, const float* __restrict__ part) {
  const int c = blockIdx.x * 256 + threadIdx.x;
  const int chunk = blockIdx.y, b = blockIdx.z;
  if (c >= ZC) return;
  float s = part[((size_t)b * NCH + chunk) * ZC + c];
  size_t base = ((size_t)b * LL + (size_t)chunk * CH) * ZC + c;
#pragma unroll 4
  for (int i = 0; i < CH; ++i) {
    const size_t idx = base + (size_t)i * ZC;
    s += merged[idx];
    merged[idx] = s;
  }
}

// ---------------- fold norm_scale into head weights (bf16) ----------------
__global__ __launch_bounds__(256) void wprime_kernel(
    const float* __restrict__ W_re, const float* __restrict__ W_im,
    const float* __restrict__ ns, u16* __restrict__ wp) {
  const int i = blockIdx.x * 256 + threadIdx.x;   // 0..2047
  if (i < 1024) wp[i] = f2bf(ns[i >> 5] * W_re[i]);
  else {
    const int j = i - 1024;
    wp[i] = f2bf(ns[32 + (j >> 5)] * W_im[j]);
  }
}

// ---------------- norm_head via MFMA ----------------
// Block = 8 bl rows (4 waves x 2 rows). Per (bl,k) row: scale from raw row
// sums, y = [re;im]*scale @ [Wre';Wim'] via 16x16x32 bf16 MFMA, g = y*gate
// written bf16 in-place into merged row head (den read before any write).
__global__ __launch_bounds__(256) void norm_head_mfma(
    float* merged, const u16* __restrict__ z, const float* __restrict__ kern,
    const u16* __restrict__ wp) {
  __shared__ u16 zw[11 * GLD];       // skewed gate-z tile
  __shared__ float skern[4 * KLD];   // skewed gate conv weights
  const int tid = threadIdx.x;
  const int r0 = blockIdx.x * 8;
  const bool first = ((r0 & (LL - 1)) == 0);
  const int lane = tid & 63, wv = tid >> 6;
  const int lm = lane & 15, lq = lane >> 4;

  // stage z gate cols (1024..2047), rows r0-3 .. r0+7, with skew
  for (int idx = tid; idx < 11 * 128; idx += 256) {
    const int i = idx >> 7, c8 = idx & 127;
    s16x8 v = {0, 0, 0, 0, 0, 0, 0, 0};
    if (!(first && i < 3))
      v = *(const s16x8*)(z + (size_t)(r0 - 3 + i) * ZLD + 1024 + c8 * 8);
    *(s16x8*)&zw[i * GLD + c8 * 8 + (c8 >> 4) * 16] = v;
  }
  // stage gate conv weights (f32) with skew
  for (int idx = tid; idx < 4 * 256; idx += 256) {
    const int w = idx >> 8, c4 = idx & 255;
    float4 v = *(const float4*)(kern + w * ZC + 1024 + c4 * 4);
    *(float4*)&skern[w * KLD + c4 * 4 + (c4 >> 5) * 8] = v;
  }

  // B fragments (same for all rows): lane(lm,lq) holds W'[lq*8+j][nt*16+lm]
  s16x8 bre[2], bim[2];
#pragma unroll
  for (int nt = 0; nt < 2; ++nt)
#pragma unroll
    for (int jj = 0; jj < 8; ++jj) {
      bre[nt][jj] = (short)wp[(lq * 8 + jj) * 32 + nt * 16 + lm];
      bim[nt][jj] = (short)wp[1024 + (lq * 8 + jj) * 32 + nt * 16 + lm];
    }
  __syncthreads();

  const f32x4 z4 = {0.f, 0.f, 0.f, 0.f};
#pragma unroll 1
  for (int rr2 = 0; rr2 < 2; ++rr2) {
    const int rr = wv * 2 + rr2;          // 0..7 within block
    const int bl = r0 + rr;
    float* row = merged + (size_t)bl * ZC;
    // den for BOTH k-halves, before any write to this row
    const float den0 = row[lm], den1 = row[16 + lm];

#pragma unroll
    for (int khalf = 0; khalf < 2; ++khalf) {
      // A loads: re/im for (bl, k = khalf*16+lm), hp = lq*8..lq*8+7
      const float* rp = row + KK + (khalf * 16 + lm) * 32 + lq * 8;
      float4 ra = *(const float4*)rp;
      float4 rb = *(const float4*)(rp + 4);
      float4 ia = *(const float4*)(rp + FLATC);
      float4 ib = *(const float4*)(rp + FLATC + 4);

      float ssq = ra.x * ra.x + ra.y * ra.y + ra.z * ra.z + ra.w * ra.w +
                  rb.x * rb.x + rb.y * rb.y + rb.z * rb.z + rb.w * rb.w +
                  ia.x * ia.x + ia.y * ia.y + ia.z * ia.z + ia.w * ia.w +
                  ib.x * ib.x + ib.y * ib.y + ib.z * ib.z + ib.w * ib.w;
      ssq += __shfl_xor(ssq, 16);
      ssq += __shfl_xor(ssq, 32);
      const float den = khalf ? den1 : den0;
      const float inv = 1.0f / fmaxf(den, 1e-4f);
      const float scale = inv * rsqrtf(ssq * inv * inv * (1.0f / 64.0f) + 1e-5f);

      s16x8 afr, afi;
      afr[0] = (short)f2bf(ra.x * scale); afr[1] = (short)f2bf(ra.y * scale);
      afr[2] = (short)f2bf(ra.z * scale); afr[3] = (short)f2bf(ra.w * scale);
      afr[4] = (short)f2bf(rb.x * scale); afr[5] = (short)f2bf(rb.y * scale);
      afr[6] = (short)f2bf(rb.z * scale); afr[7] = (short)f2bf(rb.w * scale);
      afi[0] = (short)f2bf(ia.x * scale); afi[1] = (short)f2bf(ia.y * scale);
      afi[2] = (short)f2bf(ia.z * scale); afi[3] = (short)f2bf(ia.w * scale);
      afi[4] = (short)f2bf(ib.x * scale); afi[5] = (short)f2bf(ib.y * scale);
      afi[6] = (short)f2bf(ib.z * scale); afi[7] = (short)f2bf(ib.w * scale);

      f32x4 acc[2];
#pragma unroll
      for (int nt = 0; nt < 2; ++nt) {
        acc[nt] = __builtin_amdgcn_mfma_f32_16x16x32_bf16(afr, bre[nt], z4, 0, 0, 0);
        acc[nt] = __builtin_amdgcn_mfma_f32_16x16x32_bf16(afi, bim[nt], acc[nt], 0, 0, 0);
      }

      // epilogue: D row = lq*4+r (k offset), col = lm (h offset)
      u16* grow = (u16*)row;
#pragma unroll
      for (int nt = 0; nt < 2; ++nt) {
#pragma unroll
        for (int r = 0; r < 4; ++r) {
          const int k = khalf * 16 + lq * 4 + r;
          const int o = k * 32 + nt * 16 + lm;
          const int sk = o + (o >> 7) * 8;    // skern skew
          const int sz = o + (o >> 7) * 16;   // zw skew
          float gv = bf2f(zw[(rr + 0) * GLD + sz]) * skern[0 * KLD + sk];
          gv = fmaf(bf2f(zw[(rr + 1) * GLD + sz]), skern[1 * KLD + sk], gv);
          gv = fmaf(bf2f(zw[(rr + 2) * GLD + sz]), skern[2 * KLD + sk], gv);
          gv = fmaf(bf2f(zw[(rr + 3) * GLD + sz]), skern[3 * KLD + sk], gv);
          const float sil = gv * (1.0f / (1.0f + __expf(-gv)));
          grow[o] = f2bf(acc[nt][r] * sil);
        }
      }
    }
  }
}

// ---------------- launch ----------------
extern "C" void kernel_launch(void* const* d_in, const int* in_sizes, int n_in,
                              void* d_out, int out_size, void* d_ws, size_t ws_size,
                              hipStream_t stream) {
  const float* x      = (const float*)d_in[0];
  const float* W_in   = (const float*)d_in[1];
  const float* kern   = (const float*)d_in[2];
  const float* theta  = (const float*)d_in[3];
  const float* decay  = (const float*)d_in[4];
  const float* anchor = (const float*)d_in[5];
  const float* sscale = (const float*)d_in[6];
  const float* W_re   = (const float*)d_in[7];
  const float* W_im   = (const float*)d_in[8];
  const float* nscale = (const float*)d_in[9];
  const float* W_out  = (const float*)d_in[10];
  float* out = (float*)d_out;

  // workspace layout (~199.8 MiB + 4 KB):
  char* w = (char*)d_ws;
  float* merged = (float*)w;
  u16* xbf = (u16*)w;                                  // alias: dead once gemm1 done
  u16* zbf = (u16*)(w + (size_t)BL * ZC * 4);
  u16* wobt = zbf;                                     // alias: written after norm_head
  u16* wbt = (u16*)(w + (size_t)BL * ZC * 4 + (size_t)BL * ZLD * 2);
  float* part = (float*)((char*)wbt + (size_t)NPAD * DD * 2);
  u16* wp = (u16*)(part + (size_t)BB * NCH * ZC);      // 2048 u16

  // 1) casts / transposes / weight fold
  cast_bf16_kernel<<<dim3(BL * DD / 8 / 256), 256, 0, stream>>>(x, xbf, BL * DD);
  transpose_cast_kernel<<<dim3(32, 68), 256, 0, stream>>>(W_in, wbt, DD, ZC, NPAD);
  wprime_kernel<<<dim3(8), 256, 0, stream>>>(W_re, W_im, nscale, wp);

  // 2) GEMM1: z = x @ W_in  (bf16 MFMA, bf16 out)
  gemm_bf16_mfma<1><<<dim3(NPAD / 128, BL / 128), 256, 0, stream>>>(
      xbf, wbt, zbf, DD, DD, ZLD, DD, ZC);

  // 3) conv + p_w + features -> merged
  conv_feat_kernel<<<dim3(BL / 8), 256, 0, stream>>>(zbf, kern, theta, decay,
                                                     anchor, sscale, merged);

  // 4) blocked inclusive scan over L (in-place on merged)
  {
    dim3 grid((ZC + 255) / 256, NCH, BB);
    scan_partial_kernel<<<grid, 256, 0, stream>>>(merged, part);
    dim3 grid2((ZC + 255) / 256, 1, BB);
    scan_offsets_kernel<<<grid2, 256, 0, stream>>>(part);
    scan_apply_kernel<<<grid, 256, 0, stream>>>(merged, part);
  }

  // 5) normalize + RMS + head matmuls (MFMA) + gate -> g (bf16, in-place)
  norm_head_mfma<<<dim3(BL / 8), 256, 0, stream>>>(merged, zbf, kern, wp);

  // 6) W_out^T (into dead z region), then GEMM2: out = g @ W_out (f32 out)
  transpose_cast_kernel<<<dim3(32, 32), 256, 0, stream>>>(W_out, wobt, DI, DD, DD);
  gemm_bf16_mfma<0><<<dim3(DD / 128, BL / 128), 256, 0, stream>>>(
      (const u16*)merged, wobt, out, 2 * ZC, DI, DD, DI, DD);
}

// Round 7
// 519.587 us; speedup vs baseline: 4.5144x; 1.0059x over previous
//
#include <hip/hip_runtime.h>
#include <hip/hip_bf16.h>
#include <math.h>

// ---------------- static problem config ----------------
#define BB 4
#define LL 4096
#define DD 1024
#define KK 32
#define HH 32
#define AA 4
#define CKK 4
#define DI 1024
#define ZC 2080            // 2*DI + KK
#define FLATC 1024         // K*H
#define BL (BB * LL)       // 16384
#define ZLD 2080           // z row stride (bf16)
#define NPAD 2176          // W_in^T padded rows (17*128)

// scan config
#define CH 256
#define NCH (LL / CH)      // 16

// norm_head LDS strides (skewed to break lq-stride-128 bank conflicts)
#define GLD 1136           // zw row stride in u16 : col = o + (o>>7)*16
#define KLD 1080           // skern row stride in f32: col = o + (o>>7)*8

typedef unsigned short u16;
typedef __attribute__((ext_vector_type(8))) short s16x8;
typedef __attribute__((ext_vector_type(4))) float f32x4;

__device__ __forceinline__ u16 f2bf(float f) {
  union { float f; unsigned int u; } v; v.f = f;
  unsigned int r = (v.u + 0x7FFFu + ((v.u >> 16) & 1u)) >> 16;
  return (u16)r;
}
__device__ __forceinline__ float bf2f(u16 u) {
  union { unsigned int i; float f; } x; x.i = ((unsigned int)u) << 16; return x.f;
}
__device__ __forceinline__ void gl_lds16(const void* g, void* l) {
  __builtin_amdgcn_global_load_lds(
      (const __attribute__((address_space(1))) unsigned int*)g,
      (__attribute__((address_space(3))) unsigned int*)l, 16, 0, 0);
}

// ---------------- cast f32 -> bf16 (x) ----------------
__global__ __launch_bounds__(256) void cast_bf16_kernel(
    const float* __restrict__ src, u16* __restrict__ dst, int n) {
  const int i = (blockIdx.x * 256 + threadIdx.x) * 8;
  if (i >= n) return;
  float4 a = *(const float4*)(src + i);
  float4 b = *(const float4*)(src + i + 4);
  s16x8 v;
  v[0] = (short)f2bf(a.x); v[1] = (short)f2bf(a.y);
  v[2] = (short)f2bf(a.z); v[3] = (short)f2bf(a.w);
  v[4] = (short)f2bf(b.x); v[5] = (short)f2bf(b.y);
  v[6] = (short)f2bf(b.z); v[7] = (short)f2bf(b.w);
  *(s16x8*)(dst + i) = v;
}

// ---------------- transpose + cast: src[R][C] f32 -> dst[Cpad][R] bf16 ----
__global__ __launch_bounds__(256) void transpose_cast_kernel(
    const float* __restrict__ src, u16* __restrict__ dst,
    int R, int C, int Cpad) {
  __shared__ float t[32][33];
  const int tid = threadIdx.x;
  const int r0 = blockIdx.x * 32, c0 = blockIdx.y * 32;
  const int lr = tid >> 5, lc = tid & 31;
#pragma unroll
  for (int i = 0; i < 4; ++i) {
    const int r = r0 + i * 8 + lr, c = c0 + lc;
    float v = 0.f;
    if (r < R && c < C) v = src[(size_t)r * C + c];
    t[lc][i * 8 + lr] = v;
  }
  __syncthreads();
#pragma unroll
  for (int i = 0; i < 4; ++i) {
    const int dr = c0 + i * 8 + lr;   // row in dst = col in src
    const int dc = r0 + lc;           // col in dst = row in src
    if (dr < Cpad && dc < R) dst[(size_t)dr * R + dc] = f2bf(t[i * 8 + lr][lc]);
  }
}

// ---------------- bf16 MFMA GEMM: C[M,N] = A[M,K] * Bt[N,K]^T -------------
// 128x128 tile, 4 waves in 2x2, 16x16x32 MFMA, BK=64, global_load_lds(16B).
// Dispatch swizzle: blockIdx.x = ROW tile (fast-varying), blockIdx.y = COL
// tile. Same-row blocks are spaced by gridDim.x (multiple of 8) -> same XCD
// under round-robin dispatch, so the A row-stripe stays in that XCD's L2
// across all column tiles.
template <int OUT_BF16>
__global__ __launch_bounds__(256) void gemm_bf16_mfma(
    const u16* __restrict__ A, const u16* __restrict__ Bt, void* __restrict__ C,
    int lda, int ldb, int ldc, int Kd, int Ncols) {
  __shared__ u16 As[8192];   // 16 blocks x 512 elems
  __shared__ u16 Bs[8192];
  const int tid = threadIdx.x;
  const int lane = tid & 63, wv = tid >> 6;
  const int lm = lane & 15, lq = lane >> 4;
  const int bm = blockIdx.x * 128, bn = blockIdx.y * 128;
  const int wrow = (wv & 1) * 64, wcol = (wv >> 1) * 64;

  const f32x4 z4 = {0.f, 0.f, 0.f, 0.f};
  f32x4 acc[4][4];
#pragma unroll
  for (int i = 0; i < 4; ++i)
#pragma unroll
    for (int j = 0; j < 4; ++j) acc[i][j] = z4;

  for (int k0 = 0; k0 < Kd; k0 += 64) {
    __syncthreads();
#pragma unroll
    for (int t = 0; t < 8; ++t) {
      const int idx = wv * 8 + t;             // 0..31
      if (idx < 16) {                          // A block (mt, kt)
        const int mt = idx >> 1, kt = idx & 1;
        const u16* g = A + (size_t)(bm + mt * 16 + lm) * lda + k0 + kt * 32 + lq * 8;
        gl_lds16(g, &As[idx * 512]);
      } else {                                 // B block (nt, kt)
        const int bidx = idx - 16;
        const int nt = bidx >> 1, kt = bidx & 1;
        const u16* g = Bt + (size_t)(bn + nt * 16 + lm) * ldb + k0 + kt * 32 + lq * 8;
        gl_lds16(g, &Bs[bidx * 512]);
      }
    }
    __syncthreads();
#pragma unroll
    for (int kt = 0; kt < 2; ++kt) {
      s16x8 af[4], bfb[4];
#pragma unroll
      for (int i = 0; i < 4; ++i) {
        const int mt = (wrow >> 4) + i;
        af[i] = *(const s16x8*)&As[(mt * 2 + kt) * 512 + lane * 8];
        const int nt = (wcol >> 4) + i;
        bfb[i] = *(const s16x8*)&Bs[(nt * 2 + kt) * 512 + lane * 8];
      }
#pragma unroll
      for (int i = 0; i < 4; ++i)
#pragma unroll
        for (int j = 0; j < 4; ++j)
          acc[i][j] = __builtin_amdgcn_mfma_f32_16x16x32_bf16(af[i], bfb[j], acc[i][j], 0, 0, 0);
    }
  }
  // epilogue: C/D layout col = lane&15, row = (lane>>4)*4 + reg
#pragma unroll
  for (int i = 0; i < 4; ++i) {
#pragma unroll
    for (int j = 0; j < 4; ++j) {
#pragma unroll
      for (int r = 0; r < 4; ++r) {
        const int row = bm + wrow + i * 16 + lq * 4 + r;
        const int col = bn + wcol + j * 16 + lm;
        if (col < Ncols) {
          if (OUT_BF16)
            ((u16*)C)[(size_t)row * ldc + col] = f2bf(acc[i][j][r]);
          else
            ((float*)C)[(size_t)row * ldc + col] = acc[i][j][r];
        }
      }
    }
  }
}

// ---------------- conv + p_w + phase features (reads z bf16) --------------
__global__ __launch_bounds__(256) void conv_feat_kernel(
    const u16* __restrict__ z, const float* __restrict__ kern,
    const float* __restrict__ theta, const float* __restrict__ decay,
    const float* __restrict__ anchor, const float* __restrict__ sscale,
    float* __restrict__ merged) {
  __shared__ u16 zw[11 * ZLD];    // 45760 B
  __shared__ float spw[8][32];
  const int tid = threadIdx.x;
  const int r0 = blockIdx.x * 8;
  const bool first = ((r0 & (LL - 1)) == 0);

  for (int idx = tid; idx < 11 * (ZLD / 8); idx += 256) {
    const int i = idx / (ZLD / 8);
    const int c8 = idx - i * (ZLD / 8);
    s16x8 v = {0, 0, 0, 0, 0, 0, 0, 0};
    if (!(first && i < 3))
      v = *(const s16x8*)(z + (size_t)(r0 - 3 + i) * ZLD + c8 * 8);
    *(s16x8*)&zw[i * ZLD + c8 * 8] = v;
  }
  __syncthreads();

  {  // scores -> p_w (8 rows x 32 heads = 256 threads)
    const int rr = tid >> 5, k = tid & 31;
    float v = 0.f;
#pragma unroll
    for (int w = 0; w < CKK; ++w)
      v = fmaf(bf2f(zw[(rr + w) * ZLD + 2048 + k]), kern[w * ZC + 2048 + k], v);
    const int l = (r0 + rr) & (LL - 1);
    const float slope = (k < KK - AA) ? decay[k] : anchor[k - (KK - AA)];
    const float sp = log1pf(__expf(slope));
    const float lw = (k < KK - AA) ? (-sp * (float)(LL - 1 - l)) : (-sp * (float)l);
    const float p = __expf(sscale[k] * v + lw);
    spw[rr][k] = p;
    merged[(size_t)(r0 + rr) * ZC + k] = p;
  }
  __syncthreads();

#pragma unroll 1
  for (int it = 0; it < 4; ++it) {
    const int c = it * 256 + tid;   // 0..1023
    const float kw0 = kern[0 * ZC + c], kw1 = kern[1 * ZC + c];
    const float kw2 = kern[2 * ZC + c], kw3 = kern[3 * ZC + c];
    const float th = theta[c];
    float zv[11];
#pragma unroll
    for (int i = 0; i < 11; ++i) zv[i] = bf2f(zw[i * ZLD + c]);
#pragma unroll
    for (int rr = 0; rr < 8; ++rr) {
      float v = zv[rr] * kw0;
      v = fmaf(zv[rr + 1], kw1, v);
      v = fmaf(zv[rr + 2], kw2, v);
      v = fmaf(zv[rr + 3], kw3, v);
      const float phi = v * th;
      float sv, cv;
      __sincosf(phi, &sv, &cv);
      const float p = spw[rr][c >> 5];
      float* mrow = merged + (size_t)(r0 + rr) * ZC;
      mrow[KK + c] = p * cv;
      mrow[KK + FLATC + c] = p * sv;
    }
  }
}

// ---------------- blocked scan over L ----------------
__global__ __launch_bounds__(256) void scan_partial_kernel(
    const float* __restrict__ merged, float* __restrict__ part) {
  const int c = blockIdx.x * 256 + threadIdx.x;
  const int chunk = blockIdx.y, b = blockIdx.z;
  if (c >= ZC) return;
  size_t base = ((size_t)b * LL + (size_t)chunk * CH) * ZC + c;
  float s = 0.f;
#pragma unroll 8
  for (int i = 0; i < CH; ++i) s += merged[base + (size_t)i * ZC];
  part[((size_t)b * NCH + chunk) * ZC + c] = s;
}

__global__ __launch_bounds__(256) void scan_offsets_kernel(float* __restrict__ part) {
  const int c = blockIdx.x * 256 + threadIdx.x;
  const int b = blockIdx.z;
  if (c >= ZC) return;
  float run = 0.f;
#pragma unroll
  for (int i = 0; i < NCH; ++i) {
    const size_t idx = ((size_t)b * NCH + i) * ZC + c;
    const float t = part[idx];
    part[idx] = run;
    run += t;
  }
}

__global__ __launch_bounds__(256) void scan_apply_kernel(
    float* __restrict__ merged, const float* __restrict__ part) {
  const int c = blockIdx.x * 256 + threadIdx.x;
  const int chunk = blockIdx.y, b = blockIdx.z;
  if (c >= ZC) return;
  float s = part[((size_t)b * NCH + chunk) * ZC + c];
  size_t base = ((size_t)b * LL + (size_t)chunk * CH) * ZC + c;
#pragma unroll 4
  for (int i = 0; i < CH; ++i) {
    const size_t idx = base + (size_t)i * ZC;
    s += merged[idx];
    merged[idx] = s;
  }
}

// ---------------- fold norm_scale into head weights (bf16) ----------------
__global__ __launch_bounds__(256) void wprime_kernel(
    const float* __restrict__ W_re, const float* __restrict__ W_im,
    const float* __restrict__ ns, u16* __restrict__ wp) {
  const int i = blockIdx.x * 256 + threadIdx.x;   // 0..2047
  if (i < 1024) wp[i] = f2bf(ns[i >> 5] * W_re[i]);
  else {
    const int j = i - 1024;
    wp[i] = f2bf(ns[32 + (j >> 5)] * W_im[j]);
  }
}

// ---------------- norm_head via MFMA ----------------
// Block = 8 bl rows (4 waves x 2 rows). Per (bl,k) row: scale from raw row
// sums, y = [re;im]*scale @ [Wre';Wim'] via 16x16x32 bf16 MFMA, g = y*gate
// written bf16 in-place into merged row head (den read before any write).
__global__ __launch_bounds__(256) void norm_head_mfma(
    float* merged, const u16* __restrict__ z, const float* __restrict__ kern,
    const u16* __restrict__ wp) {
  __shared__ u16 zw[11 * GLD];       // skewed gate-z tile
  __shared__ float skern[4 * KLD];   // skewed gate conv weights
  const int tid = threadIdx.x;
  const int r0 = blockIdx.x * 8;
  const bool first = ((r0 & (LL - 1)) == 0);
  const int lane = tid & 63, wv = tid >> 6;
  const int lm = lane & 15, lq = lane >> 4;

  // stage z gate cols (1024..2047), rows r0-3 .. r0+7, with skew
  for (int idx = tid; idx < 11 * 128; idx += 256) {
    const int i = idx >> 7, c8 = idx & 127;
    s16x8 v = {0, 0, 0, 0, 0, 0, 0, 0};
    if (!(first && i < 3))
      v = *(const s16x8*)(z + (size_t)(r0 - 3 + i) * ZLD + 1024 + c8 * 8);
    *(s16x8*)&zw[i * GLD + c8 * 8 + (c8 >> 4) * 16] = v;
  }
  // stage gate conv weights (f32) with skew
  for (int idx = tid; idx < 4 * 256; idx += 256) {
    const int w = idx >> 8, c4 = idx & 255;
    float4 v = *(const float4*)(kern + w * ZC + 1024 + c4 * 4);
    *(float4*)&skern[w * KLD + c4 * 4 + (c4 >> 5) * 8] = v;
  }

  // B fragments (same for all rows): lane(lm,lq) holds W'[lq*8+j][nt*16+lm]
  s16x8 bre[2], bim[2];
#pragma unroll
  for (int nt = 0; nt < 2; ++nt)
#pragma unroll
    for (int jj = 0; jj < 8; ++jj) {
      bre[nt][jj] = (short)wp[(lq * 8 + jj) * 32 + nt * 16 + lm];
      bim[nt][jj] = (short)wp[1024 + (lq * 8 + jj) * 32 + nt * 16 + lm];
    }
  __syncthreads();

  const f32x4 z4 = {0.f, 0.f, 0.f, 0.f};
#pragma unroll 1
  for (int rr2 = 0; rr2 < 2; ++rr2) {
    const int rr = wv * 2 + rr2;          // 0..7 within block
    const int bl = r0 + rr;
    float* row = merged + (size_t)bl * ZC;
    // den for BOTH k-halves, before any write to this row
    const float den0 = row[lm], den1 = row[16 + lm];

#pragma unroll
    for (int khalf = 0; khalf < 2; ++khalf) {
      // A loads: re/im for (bl, k = khalf*16+lm), hp = lq*8..lq*8+7
      const float* rp = row + KK + (khalf * 16 + lm) * 32 + lq * 8;
      float4 ra = *(const float4*)rp;
      float4 rb = *(const float4*)(rp + 4);
      float4 ia = *(const float4*)(rp + FLATC);
      float4 ib = *(const float4*)(rp + FLATC + 4);

      float ssq = ra.x * ra.x + ra.y * ra.y + ra.z * ra.z + ra.w * ra.w +
                  rb.x * rb.x + rb.y * rb.y + rb.z * rb.z + rb.w * rb.w +
                  ia.x * ia.x + ia.y * ia.y + ia.z * ia.z + ia.w * ia.w +
                  ib.x * ib.x + ib.y * ib.y + ib.z * ib.z + ib.w * ib.w;
      ssq += __shfl_xor(ssq, 16);
      ssq += __shfl_xor(ssq, 32);
      const float den = khalf ? den1 : den0;
      const float inv = 1.0f / fmaxf(den, 1e-4f);
      const float scale = inv * rsqrtf(ssq * inv * inv * (1.0f / 64.0f) + 1e-5f);

      s16x8 afr, afi;
      afr[0] = (short)f2bf(ra.x * scale); afr[1] = (short)f2bf(ra.y * scale);
      afr[2] = (short)f2bf(ra.z * scale); afr[3] = (short)f2bf(ra.w * scale);
      afr[4] = (short)f2bf(rb.x * scale); afr[5] = (short)f2bf(rb.y * scale);
      afr[6] = (short)f2bf(rb.z * scale); afr[7] = (short)f2bf(rb.w * scale);
      afi[0] = (short)f2bf(ia.x * scale); afi[1] = (short)f2bf(ia.y * scale);
      afi[2] = (short)f2bf(ia.z * scale); afi[3] = (short)f2bf(ia.w * scale);
      afi[4] = (short)f2bf(ib.x * scale); afi[5] = (short)f2bf(ib.y * scale);
      afi[6] = (short)f2bf(ib.z * scale); afi[7] = (short)f2bf(ib.w * scale);

      f32x4 acc[2];
#pragma unroll
      for (int nt = 0; nt < 2; ++nt) {
        acc[nt] = __builtin_amdgcn_mfma_f32_16x16x32_bf16(afr, bre[nt], z4, 0, 0, 0);
        acc[nt] = __builtin_amdgcn_mfma_f32_16x16x32_bf16(afi, bim[nt], acc[nt], 0, 0, 0);
      }

      // epilogue: D row = lq*4+r (k offset), col = lm (h offset)
      u16* grow = (u16*)row;
#pragma unroll
      for (int nt = 0; nt < 2; ++nt) {
#pragma unroll
        for (int r = 0; r < 4; ++r) {
          const int k = khalf * 16 + lq * 4 + r;
          const int o = k * 32 + nt * 16 + lm;
          const int sk = o + (o >> 7) * 8;    // skern skew
          const int sz = o + (o >> 7) * 16;   // zw skew
          float gv = bf2f(zw[(rr + 0) * GLD + sz]) * skern[0 * KLD + sk];
          gv = fmaf(bf2f(zw[(rr + 1) * GLD + sz]), skern[1 * KLD + sk], gv);
          gv = fmaf(bf2f(zw[(rr + 2) * GLD + sz]), skern[2 * KLD + sk], gv);
          gv = fmaf(bf2f(zw[(rr + 3) * GLD + sz]), skern[3 * KLD + sk], gv);
          const float sil = gv * (1.0f / (1.0f + __expf(-gv)));
          grow[o] = f2bf(acc[nt][r] * sil);
        }
      }
    }
  }
}

// ---------------- launch ----------------
extern "C" void kernel_launch(void* const* d_in, const int* in_sizes, int n_in,
                              void* d_out, int out_size, void* d_ws, size_t ws_size,
                              hipStream_t stream) {
  const float* x      = (const float*)d_in[0];
  const float* W_in   = (const float*)d_in[1];
  const float* kern   = (const float*)d_in[2];
  const float* theta  = (const float*)d_in[3];
  const float* decay  = (const float*)d_in[4];
  const float* anchor = (const float*)d_in[5];
  const float* sscale = (const float*)d_in[6];
  const float* W_re   = (const float*)d_in[7];
  const float* W_im   = (const float*)d_in[8];
  const float* nscale = (const float*)d_in[9];
  const float* W_out  = (const float*)d_in[10];
  float* out = (float*)d_out;

  // workspace layout (~199.8 MiB + 4 KB):
  char* w = (char*)d_ws;
  float* merged = (float*)w;
  u16* xbf = (u16*)w;                                  // alias: dead once gemm1 done
  u16* zbf = (u16*)(w + (size_t)BL * ZC * 4);
  u16* wobt = zbf;                                     // alias: written after norm_head
  u16* wbt = (u16*)(w + (size_t)BL * ZC * 4 + (size_t)BL * ZLD * 2);
  float* part = (float*)((char*)wbt + (size_t)NPAD * DD * 2);
  u16* wp = (u16*)(part + (size_t)BB * NCH * ZC);      // 2048 u16

  // 1) casts / transposes / weight fold
  cast_bf16_kernel<<<dim3(BL * DD / 8 / 256), 256, 0, stream>>>(x, xbf, BL * DD);
  transpose_cast_kernel<<<dim3(32, 68), 256, 0, stream>>>(W_in, wbt, DD, ZC, NPAD);
  wprime_kernel<<<dim3(8), 256, 0, stream>>>(W_re, W_im, nscale, wp);

  // 2) GEMM1: z = x @ W_in  (bf16 MFMA, bf16 out). grid.x = row tiles.
  gemm_bf16_mfma<1><<<dim3(BL / 128, NPAD / 128), 256, 0, stream>>>(
      xbf, wbt, zbf, DD, DD, ZLD, DD, ZC);

  // 3) conv + p_w + features -> merged
  conv_feat_kernel<<<dim3(BL / 8), 256, 0, stream>>>(zbf, kern, theta, decay,
                                                     anchor, sscale, merged);

  // 4) blocked inclusive scan over L (in-place on merged)
  {
    dim3 grid((ZC + 255) / 256, NCH, BB);
    scan_partial_kernel<<<grid, 256, 0, stream>>>(merged, part);
    dim3 grid2((ZC + 255) / 256, 1, BB);
    scan_offsets_kernel<<<grid2, 256, 0, stream>>>(part);
    scan_apply_kernel<<<grid, 256, 0, stream>>>(merged, part);
  }

  // 5) normalize + RMS + head matmuls (MFMA) + gate -> g (bf16, in-place)
  norm_head_mfma<<<dim3(BL / 8), 256, 0, stream>>>(merged, zbf, kern, wp);

  // 6) W_out^T (into dead z region), then GEMM2: out = g @ W_out (f32 out)
  transpose_cast_kernel<<<dim3(32, 32), 256, 0, stream>>>(W_out, wobt, DI, DD, DD);
  gemm_bf16_mfma<0><<<dim3(BL / 128, DD / 128), 256, 0, stream>>>(
      (const u16*)merged, wobt, out, 2 * ZC, DI, DD, DI, DD);
}